// Round 7
// baseline (212.905 us; speedup 1.0000x reference)
//
#include <hip/hip_runtime.h>
#include <hip/hip_bf16.h>
#include <math.h>

// Problem constants (from reference)
constexpr int B = 8;
constexpr int S = 2048;
constexpr int D = 512;
constexpr int P = 64;
constexpr float SCALE = 0.125f;  // 1/sqrt(P)

typedef short bf16x8 __attribute__((ext_vector_type(8)));
typedef short s16x4 __attribute__((ext_vector_type(4)));
typedef float f32x4 __attribute__((ext_vector_type(4)));

__device__ __forceinline__ unsigned short f2bf(float x) {
  __hip_bfloat16 h = __float2bfloat16(x);
  return __builtin_bit_cast(unsigned short, h);
}
__device__ __forceinline__ float bf2f(unsigned short u) {
  unsigned int v = (unsigned int)u << 16;
  return __builtin_bit_cast(float, v);
}

// ===========================================================================
// Fragment-packed layouts: every MFMA fragment is a contiguous 64-lane x 16 B
// = 1 KB lane-ordered chunk -> one coalesced dwordx4 per consumer load.
//  Bfrag  [12 ntile][16 k16][64 lane][8]   : WqWkWv cat (192 cols, K=512)
//  Wofrag [32 ct][2 h][64 lane][8]         : Wo (512 cols, K=64)
//  qfrag/kfrag [b][128 tile][2 h][64][8]   : tile=16 rows, h=K-half
//  vfrag  [b][64 tb][4 pc][64][8]          : tb=32 t's, pc=16 p's (t = K dim)
// Round-7 changes (evidence: attn r2 counters MfmaUtil 6% / VALUBusy 14% /
// Occupancy 34% = latency-bound; grid 256 = exactly 1 block/CU so occupancy
// is structurally capped at 4 waves/SIMD):
//  * attn block halved to 32 q-rows -> grid 512 -> 2 blocks/CU co-resident.
//    LDS cut to ~70 KB/block: e-tile single-buffered (same-wave DS ordering
//    makes the double-buffer a no-op), epilogue combine split into two
//    p-phases over a 64 KB pacc aliasing e.  Main-loop body is the verified
//    round-5 body unchanged.
//  * qkv reverted to the round-5 version (round-6 restructure was neutral;
//    spill theory for qkv refuted).
// ===========================================================================

// ---------------------------------------------------------------------------
// Kernel 0: weight prep -> fragment-packed bf16.
// ---------------------------------------------------------------------------
__global__ __launch_bounds__(256) void prep_w(
    const float* __restrict__ Wq, const float* __restrict__ Wk,
    const float* __restrict__ Wv, const float* __restrict__ Wo,
    unsigned short* __restrict__ Bfrag, unsigned short* __restrict__ Wofrag) {
  const int i = blockIdx.x * 256 + threadIdx.x;
  if (i < 192 * 512) {
    const int d = i / 192;        // K index 0..511
    const int n = i - d * 192;    // output col 0..191
    const float* W = (n < 64) ? Wq : (n < 128) ? Wk : Wv;
    const float val = W[d * 64 + (n & 63)];
    const int nt = n >> 4, l15 = n & 15;
    const int k16 = d >> 5, l4 = (d >> 3) & 3, j = d & 7;
    Bfrag[(((nt * 16 + k16) * 4 + l4) * 16 + l15) * 8 + j] = f2bf(val);
  }
  if (i < 64 * 512) {
    const int k = i >> 9;   // 0..63   (P dim)
    const int n = i & 511;  // 0..511  (D dim)
    const float val = Wo[k * 512 + n];
    const int ct = n >> 4, l15 = n & 15;
    const int h = k >> 5, l4 = (k >> 3) & 3, j = k & 7;
    Wofrag[(((ct * 2 + h) * 4 + l4) * 16 + l15) * 8 + j] = f2bf(val);
  }
}

// ---------------------------------------------------------------------------
// Kernel 1: QKV projection (round-5 version).  Grid 1024 x 256.
// Block = 16 rows x 192 cols; wave w owns n-tiles {w (q), 4+w (k), 8+w (v)}.
// q/k use OPERAND-SWAPPED MFMA -> C[p][s]: lane holds a p-run of 4 -> one
// packed 8B store per matrix.  v stays C[s][p].  K-loop staggered; 1 barrier.
// ---------------------------------------------------------------------------
__global__ __launch_bounds__(256)
__attribute__((amdgpu_waves_per_eu(4, 4))) void qkv_mfma(
    const float* __restrict__ query, const unsigned short* __restrict__ Bfrag,
    const float* __restrict__ bq, const float* __restrict__ bk,
    const float* __restrict__ bv, unsigned short* __restrict__ qfrag,
    unsigned short* __restrict__ kfrag, unsigned short* __restrict__ vfrag) {
  __shared__ __align__(16) unsigned short Aq[16 * 512];  // 16 KB

  const int tid = threadIdx.x;
  const int w = tid >> 6;
  const int l = tid & 63;
  const int l15 = l & 15;
  const int l4 = l >> 4;
  const int s0 = blockIdx.x * 16;
  const int kb0 = blockIdx.x & 15;  // K-phase stagger

  // ---- Prologue: 16 query rows fp32 -> bf16 swizzled LDS tile.
  const float* qsrc = query + (size_t)s0 * D;
#pragma unroll
  for (int step = 0; step < 4; ++step) {
    const int row = step * 4 + w;  // wave-uniform
    const float* pf = qsrc + row * D + l * 8;
    const float4 x = *(const float4*)pf;
    const float4 y = *(const float4*)(pf + 4);
    bf16x8 u;
    u[0] = (short)f2bf(x.x); u[1] = (short)f2bf(x.y);
    u[2] = (short)f2bf(x.z); u[3] = (short)f2bf(x.w);
    u[4] = (short)f2bf(y.x); u[5] = (short)f2bf(y.y);
    u[6] = (short)f2bf(y.z); u[7] = (short)f2bf(y.w);
    *(bf16x8*)&Aq[row * 512 + ((l ^ (row & 7)) << 3)] = u;
  }
  __syncthreads();  // the ONLY barrier

  f32x4 acc[3];
#pragma unroll
  for (int m = 0; m < 3; ++m) acc[m] = (f32x4){0.f, 0.f, 0.f, 0.f};

#pragma unroll
  for (int kk = 0; kk < 16; ++kk) {
    const int k16 = (kk + kb0) & 15;  // staggered K order
    const int aslot = (k16 * 4 + l4) ^ (l15 & 7);
    const bf16x8 af = *(const bf16x8*)&Aq[l15 * 512 + (aslot << 3)];
    const bf16x8 bfq =
        *(const bf16x8*)(Bfrag + ((size_t)(w * 16 + k16) * 64 + l) * 8);
    const bf16x8 bfk =
        *(const bf16x8*)(Bfrag + ((size_t)((4 + w) * 16 + k16) * 64 + l) * 8);
    const bf16x8 bfv =
        *(const bf16x8*)(Bfrag + ((size_t)((8 + w) * 16 + k16) * 64 + l) * 8);
    acc[0] = __builtin_amdgcn_mfma_f32_16x16x32_bf16(bfq, af, acc[0], 0, 0, 0);
    acc[1] = __builtin_amdgcn_mfma_f32_16x16x32_bf16(bfk, af, acc[1], 0, 0, 0);
    acc[2] = __builtin_amdgcn_mfma_f32_16x16x32_bf16(af, bfv, acc[2], 0, 0, 0);
  }

  // ---- Epilogue: bias + packed coalesced fragment stores.
  const int bidx = s0 >> 11;
  const size_t bbase = (size_t)bidx * (S * P);
  const int S0 = s0 & 2047;

  // q/k (swapped): lane holds p = w*16 + l4*4 + r, s = s0 + l15.
  const int p0 = w * 16 + l4 * 4;
  const float4 bq4 = *(const float4*)(bq + p0);
  const float4 bk4 = *(const float4*)(bk + p0);
  const size_t qkoff =
      bbase +
      ((((size_t)(S0 >> 4) * 2 + (p0 >> 5)) * 4 + ((p0 >> 3) & 3)) * 16 +
       l15) * 8 +
      (p0 & 7);
  s16x4 pq, pkk;
  pq[0] = (short)f2bf((acc[0][0] + bq4.x) * SCALE);
  pq[1] = (short)f2bf((acc[0][1] + bq4.y) * SCALE);
  pq[2] = (short)f2bf((acc[0][2] + bq4.z) * SCALE);
  pq[3] = (short)f2bf((acc[0][3] + bq4.w) * SCALE);
  pkk[0] = (short)f2bf(acc[1][0] + bk4.x);
  pkk[1] = (short)f2bf(acc[1][1] + bk4.y);
  pkk[2] = (short)f2bf(acc[1][2] + bk4.z);
  pkk[3] = (short)f2bf(acc[1][3] + bk4.w);
  *(s16x4*)(qfrag + qkoff) = pq;
  *(s16x4*)(kfrag + qkoff) = pkk;

  // v (normal): lane holds p = w*16 + l15, t = S0 + l4*4 + r.
  const float bbv = bv[w * 16 + l15];
  const int chv = ((S0 >> 3) + (l4 >> 1)) & 3;
  const size_t voff =
      bbase + ((((size_t)(S0 >> 5) * 4 + w) * 4 + chv) * 16 + l15) * 8 +
      (l4 & 1) * 4;
  s16x4 pv;
  pv[0] = (short)f2bf(acc[2][0] + bbv);
  pv[1] = (short)f2bf(acc[2][1] + bbv);
  pv[2] = (short)f2bf(acc[2][2] + bbv);
  pv[3] = (short)f2bf(acc[2][3] + bbv);
  *(s16x4*)(vfrag + voff) = pv;
}

// ---------------------------------------------------------------------------
// Kernel 2: flash attention + fused output projection.
// Grid 512 x 1024 thr (16 waves).  Block = 32 q-rows of one batch
// (blk&7=batch -> XCD L2 pinning).  LDS ~70 KB -> 2 blocks/CU -> 8 waves/SIMD
// (the latency-bound fix; r2 counters showed 6% Mfma / 14% VALU / 34% occ).
// Wave w = th (0..15) owns t in [th*128, th*128+128): 2 windows of 64 t,
// window order staggered by qt&1.  e-tile SINGLE-buffered 4 KB/wave
// (same-wave DS ops execute in order; dbuf was a no-op).
// QK^T operand-SWAPPED: scores D[t][q] (lane: t-run of 4, q=l15) -> exp
// packs into one s16x4 store per n-tile into the verified layout:
//   elem(q, t) at byte  st*2048 + q*128 + ((t*2) ^ ((q&7)<<4))
// PV reads it back with the verified swizzled ds_read_b128:
//   ae at byte          st*2048 + l15*128 + ((hf*64 + l4*16) ^ ((l15&7)<<4))
// Epilogue: two p-phase combine.  pacc [16 src][32 row][32 col] f32 = 64 KB
// aliasing e; writer col = ((pcx ^ ((row>>2)&1))<<4) + l15 (2-way banks);
// reader col = ((w>>3) ^ (w&1))*16 + l15 (matches writer algebraically).
// All 16 waves dump / all 16 waves combine (1 value per lane per phase).
// Then wnorm [32][64] bf16 (4 KB) -> fused Wo projection.
// ---------------------------------------------------------------------------
__global__ __launch_bounds__(1024)
__attribute__((amdgpu_waves_per_eu(8))) void attn_fused(
    const unsigned short* __restrict__ qfrag,
    const unsigned short* __restrict__ kfrag,
    const unsigned short* __restrict__ vfrag,
    const unsigned short* __restrict__ Wofrag, const float* __restrict__ bo,
    float* __restrict__ out) {
  // smem: main loop e = 16 waves x 4 KB = 64 KB at offset 0;
  //       epilogue pacc [16][32][32] f32 = 64 KB aliases offset 0;
  //       wnorm [32][64] bf16 = 4 KB at offset 65536.  Total 68 KB + l_s.
  __shared__ __align__(16) unsigned char smem[69632];
  __shared__ float l_s[16][32];

  const int tid = threadIdx.x;
  const int w = tid >> 6;   // th 0..15
  const int lane = tid & 63;
  const int l15 = lane & 15;
  const int l4 = lane >> 4;

  const int blk = blockIdx.x;  // 0..511
  const int b = blk & 7;
  const int qt = blk >> 3;     // 0..63
  const int s0 = qt * 32;
  const int wst = qt & 1;      // window-phase stagger

  const size_t bbase = (size_t)b * (S * P);
  const unsigned short* qf = qfrag + bbase;
  const unsigned short* kf = kfrag + bbase;
  const unsigned short* vf = vfrag + bbase;

  unsigned char* e_w = smem + w * 4096;  // 4 KB/wave, single buffer
  const int xm = (l15 & 7) << 4;         // q-row XOR swizzle mask (bytes)

  // q A-fragments: tiles qt*2 + st.
  bf16x8 aq[2][2];
#pragma unroll
  for (int st = 0; st < 2; ++st)
#pragma unroll
    for (int h = 0; h < 2; ++h)
      aq[st][h] =
          *(const bf16x8*)(qf +
                           ((size_t)((qt * 2 + st) * 2 + h) * 64 + lane) * 8);

  f32x4 acc[2][4];
#pragma unroll
  for (int st = 0; st < 2; ++st)
#pragma unroll
    for (int pc = 0; pc < 4; ++pc) acc[st][pc] = (f32x4){0.f, 0.f, 0.f, 0.f};
  float lpart[2] = {0.f, 0.f};

  for (int win = 0; win < 2; ++win) {
    const int wi = (win + wst) & 1;     // staggered window
    const int t0 = w * 128 + wi * 64;
    unsigned char* epb = e_w;           // single buffer

    // Two 32-t half-windows; runtime loop caps register liveness.
#pragma unroll 1
    for (int hf = 0; hf < 2; ++hf) {
      // k fragments for this half (4 coalesced 1 KB loads).
      bf16x8 bkh[2][2];
#pragma unroll
      for (int j = 0; j < 2; ++j)
#pragma unroll
        for (int h = 0; h < 2; ++h)
          bkh[j][h] =
              *(const bf16x8*)(kf + ((size_t)(((t0 >> 4) + hf * 2 + j) * 2 +
                                              h) * 64 + lane) * 8);

      // QK^T + exp/pack/store per subtile.  t = (hf*2+j)*16 + l4*4 + r.
#pragma unroll
      for (int st = 0; st < 2; ++st) {
        f32x4 sc[2];
#pragma unroll
        for (int j = 0; j < 2; ++j) {
          f32x4 c = (f32x4){0.f, 0.f, 0.f, 0.f};
          c = __builtin_amdgcn_mfma_f32_16x16x32_bf16(bkh[j][0], aq[st][0], c,
                                                      0, 0, 0);
          sc[j] = __builtin_amdgcn_mfma_f32_16x16x32_bf16(bkh[j][1], aq[st][1],
                                                          c, 0, 0, 0);
        }
#pragma unroll
        for (int j = 0; j < 2; ++j) {
          s16x4 pk;
#pragma unroll
          for (int r = 0; r < 4; ++r) pk[r] = (short)f2bf(__expf(sc[j][r]));
#pragma unroll
          for (int r = 0; r < 4; ++r)
            lpart[st] += bf2f((unsigned short)pk[r]);
          *(s16x4*)(epb + st * 2048 + l15 * 128 +
                    (((hf * 2 + j) * 32 + l4 * 8) ^ xm)) = pk;
        }
      }

      // v fragments for this half (4 coalesced 1 KB loads).
      bf16x8 bvh[4];
#pragma unroll
      for (int pc = 0; pc < 4; ++pc)
        bvh[pc] =
            *(const bf16x8*)(vf + ((size_t)(((t0 >> 5) + hf) * 4 + pc) * 64 +
                                   lane) * 8);

      // PV for this half (same-wave DS ordering makes stores visible).
#pragma unroll
      for (int st = 0; st < 2; ++st) {
        const bf16x8 ae = *(const bf16x8*)(epb + st * 2048 + l15 * 128 +
                                           ((hf * 64 + l4 * 16) ^ xm));
#pragma unroll
        for (int pc = 0; pc < 4; ++pc)
          acc[st][pc] = __builtin_amdgcn_mfma_f32_16x16x32_bf16(
              ae, bvh[pc], acc[st][pc], 0, 0, 0);
      }
    }
  }

  // ---- Row-sums: intra-lane over t, then across the 4 l4-groups.
#pragma unroll
  for (int st = 0; st < 2; ++st) {
    float v = lpart[st];
    v += __shfl_xor(v, 16, 64);
    v += __shfl_xor(v, 32, 64);
    if (l4 == 0) l_s[w][st * 16 + l15] = v;
  }

  __syncthreads();  // all waves done with e-tiles before pacc aliases them

  float* pacc = (float*)smem;                               // [16][32][32]
  unsigned short* wnorm = (unsigned short*)(smem + 65536);  // [32][64]

  // Per-lane combine coordinates (fixed across phases).
  const int crow = (w & 7) * 4 + l4;               // 0..31
  const int prel = (w >> 3) * 16 + l15;            // 0..31 within p-half
  const int rc = (((w >> 3) ^ (w & 1)) << 4) + l15;  // swizzled read col
  float ls = 0.f;
#pragma unroll
  for (int s2 = 0; s2 < 16; ++s2) ls += l_s[s2][crow];
  const float inv = 1.f / ls;

#pragma unroll 1
  for (int ph = 0; ph < 2; ++ph) {
    // Dump: wave w writes acc for pc = ph*2 + {0,1}.
#pragma unroll
    for (int st = 0; st < 2; ++st)
#pragma unroll
      for (int pcx = 0; pcx < 2; ++pcx) {
        const int pc = ph * 2 + pcx;
        const int cs = ((pcx ^ (l4 & 1)) << 4) + l15;  // 2-way banks
#pragma unroll
        for (int r = 0; r < 4; ++r) {
          const int row = st * 16 + l4 * 4 + r;
          pacc[(w * 32 + row) * 32 + cs] = acc[st][pc][r];
        }
      }
    __syncthreads();

    // Combine: one (row, col) per lane, summed over all 16 sources.
    float s = 0.f;
#pragma unroll
    for (int s2 = 0; s2 < 16; ++s2) s += pacc[(s2 * 32 + crow) * 32 + rc];
    wnorm[crow * 64 + ph * 32 + prel] = f2bf(s * inv);
    __syncthreads();  // combine reads done before next dump / before proj
  }

  // ---- Fused output projection: 16 waves = (2 row-subtiles) x (8 col-64s).
  const int sub = w & 1;    // 16-row subtile
  const int chq = w >> 1;   // 64-col group (0..7)
  const bf16x8 a0 = *(const bf16x8*)&wnorm[(sub * 16 + l15) * 64 + l4 * 8];
  const bf16x8 a1 =
      *(const bf16x8*)&wnorm[(sub * 16 + l15) * 64 + 32 + l4 * 8];
  const size_t orow0 = (size_t)b * S + s0 + sub * 16;
#pragma unroll
  for (int ct = 0; ct < 4; ++ct) {
    const int ctg = chq * 4 + ((ct + (blk & 3)) & 3);  // staggered Wo tiles
    const bf16x8 b0 =
        *(const bf16x8*)(Wofrag + ((size_t)(ctg * 2 + 0) * 64 + lane) * 8);
    const bf16x8 b1 =
        *(const bf16x8*)(Wofrag + ((size_t)(ctg * 2 + 1) * 64 + lane) * 8);
    f32x4 c = (f32x4){0.f, 0.f, 0.f, 0.f};
    c = __builtin_amdgcn_mfma_f32_16x16x32_bf16(a0, b0, c, 0, 0, 0);
    c = __builtin_amdgcn_mfma_f32_16x16x32_bf16(a1, b1, c, 0, 0, 0);
    const int col = ctg * 16 + l15;
    const float bb = bo[col];
#pragma unroll
    for (int r = 0; r < 4; ++r)
      out[(orow0 + l4 * 4 + r) * D + col] = c[r] + bb;
  }
}

// ---------------------------------------------------------------------------
extern "C" void kernel_launch(void* const* d_in, const int* in_sizes, int n_in,
                              void* d_out, int out_size, void* d_ws,
                              size_t ws_size, hipStream_t stream) {
  const float* query = (const float*)d_in[0];
  // d_in[1] = attention_mask: unused (per-row additive constant -> softmax no-op)
  const float* Wq = (const float*)d_in[2];
  const float* bq = (const float*)d_in[3];
  const float* Wk = (const float*)d_in[4];
  const float* bk = (const float*)d_in[5];
  const float* Wv = (const float*)d_in[6];
  const float* bv = (const float*)d_in[7];
  const float* Wo = (const float*)d_in[8];
  const float* bo = (const float*)d_in[9];
  float* out = (float*)d_out;

  // Workspace (bf16): qfrag 2MB | kfrag 2MB | vfrag 2MB | Bfrag 192KB | Wofrag 64KB
  const size_t proj = (size_t)B * S * P;  // 1,048,576
  unsigned short* qfr = (unsigned short*)d_ws;
  unsigned short* kfr = qfr + proj;
  unsigned short* vfr = kfr + proj;
  unsigned short* Bfrag = vfr + proj;
  unsigned short* Wofrag = Bfrag + 192 * 512;

  prep_w<<<384, 256, 0, stream>>>(Wq, Wk, Wv, Wo, Bfrag, Wofrag);
  qkv_mfma<<<1024, 256, 0, stream>>>(query, Bfrag, bq, bk, bv, qfr, kfr, vfr);
  attn_fused<<<512, 1024, 0, stream>>>(qfr, kfr, vfr, Wofrag, bo, out);
}

// Round 8
// 146.718 us; speedup vs baseline: 1.4511x; 1.4511x over previous
//
#include <hip/hip_runtime.h>
#include <hip/hip_bf16.h>
#include <math.h>

// Problem constants (from reference)
constexpr int B = 8;
constexpr int S = 2048;
constexpr int D = 512;
constexpr int P = 64;
constexpr float SCALE = 0.125f;  // 1/sqrt(P)

typedef short bf16x8 __attribute__((ext_vector_type(8)));
typedef short s16x4 __attribute__((ext_vector_type(4)));
typedef float f32x4 __attribute__((ext_vector_type(4)));

__device__ __forceinline__ unsigned short f2bf(float x) {
  __hip_bfloat16 h = __float2bfloat16(x);
  return __builtin_bit_cast(unsigned short, h);
}
__device__ __forceinline__ float bf2f(unsigned short u) {
  unsigned int v = (unsigned int)u << 16;
  return __builtin_bit_cast(float, v);
}

// ===========================================================================
// Fragment-packed layouts: every MFMA fragment is a contiguous 64-lane x 16 B
// = 1 KB lane-ordered chunk -> one coalesced dwordx4 per consumer load.
//  Bfrag  [12 ntile][16 k16][64 lane][8]   : WqWkWv cat (192 cols, K=512)
//  Wofrag [32 ct][2 h][64 lane][8]         : Wo (512 cols, K=64)
//  qfrag/kfrag [b][128 tile][2 h][64][8]   : tile=16 rows, h=K-half
//  vfrag  [b][64 tb][4 pc][64][8]          : tb=32 t's, pc=16 p's (t = K dim)
// Round-8 change (evidence, round 7: waves_per_eu(8) -> VGPR_Count=32 ->
// spill exploded (WRITE 273 MB), BUT OccupancyPercent hit 69% -- the
// grid-512 / 70 KB-LDS structure delivers occupancy; the register hint was
// the bug.  Rounds 2/4/5/6 show the allocator's untouched default for
// 1024-thread MFMA kernels is 64 VGPR = exactly 8 waves/SIMD budget):
//  * attn: keep round-7 structure (its indexing passed on HW), DROP the
//    waves_per_eu hint -> allocator default 64 VGPR, spill-free round-5
//    body (~54 live), 2 blocks/CU x 16 waves = 8 waves/SIMD.
//  * qkv / prep unchanged (round-5 versions).
// ===========================================================================

// ---------------------------------------------------------------------------
// Kernel 0: weight prep -> fragment-packed bf16.
// ---------------------------------------------------------------------------
__global__ __launch_bounds__(256) void prep_w(
    const float* __restrict__ Wq, const float* __restrict__ Wk,
    const float* __restrict__ Wv, const float* __restrict__ Wo,
    unsigned short* __restrict__ Bfrag, unsigned short* __restrict__ Wofrag) {
  const int i = blockIdx.x * 256 + threadIdx.x;
  if (i < 192 * 512) {
    const int d = i / 192;        // K index 0..511
    const int n = i - d * 192;    // output col 0..191
    const float* W = (n < 64) ? Wq : (n < 128) ? Wk : Wv;
    const float val = W[d * 64 + (n & 63)];
    const int nt = n >> 4, l15 = n & 15;
    const int k16 = d >> 5, l4 = (d >> 3) & 3, j = d & 7;
    Bfrag[(((nt * 16 + k16) * 4 + l4) * 16 + l15) * 8 + j] = f2bf(val);
  }
  if (i < 64 * 512) {
    const int k = i >> 9;   // 0..63   (P dim)
    const int n = i & 511;  // 0..511  (D dim)
    const float val = Wo[k * 512 + n];
    const int ct = n >> 4, l15 = n & 15;
    const int h = k >> 5, l4 = (k >> 3) & 3, j = k & 7;
    Wofrag[(((ct * 2 + h) * 4 + l4) * 16 + l15) * 8 + j] = f2bf(val);
  }
}

// ---------------------------------------------------------------------------
// Kernel 1: QKV projection (round-5 version).  Grid 1024 x 256.
// Block = 16 rows x 192 cols; wave w owns n-tiles {w (q), 4+w (k), 8+w (v)}.
// q/k use OPERAND-SWAPPED MFMA -> C[p][s]: lane holds a p-run of 4 -> one
// packed 8B store per matrix.  v stays C[s][p].  K-loop staggered; 1 barrier.
// ---------------------------------------------------------------------------
__global__ __launch_bounds__(256)
__attribute__((amdgpu_waves_per_eu(4, 4))) void qkv_mfma(
    const float* __restrict__ query, const unsigned short* __restrict__ Bfrag,
    const float* __restrict__ bq, const float* __restrict__ bk,
    const float* __restrict__ bv, unsigned short* __restrict__ qfrag,
    unsigned short* __restrict__ kfrag, unsigned short* __restrict__ vfrag) {
  __shared__ __align__(16) unsigned short Aq[16 * 512];  // 16 KB

  const int tid = threadIdx.x;
  const int w = tid >> 6;
  const int l = tid & 63;
  const int l15 = l & 15;
  const int l4 = l >> 4;
  const int s0 = blockIdx.x * 16;
  const int kb0 = blockIdx.x & 15;  // K-phase stagger

  // ---- Prologue: 16 query rows fp32 -> bf16 swizzled LDS tile.
  const float* qsrc = query + (size_t)s0 * D;
#pragma unroll
  for (int step = 0; step < 4; ++step) {
    const int row = step * 4 + w;  // wave-uniform
    const float* pf = qsrc + row * D + l * 8;
    const float4 x = *(const float4*)pf;
    const float4 y = *(const float4*)(pf + 4);
    bf16x8 u;
    u[0] = (short)f2bf(x.x); u[1] = (short)f2bf(x.y);
    u[2] = (short)f2bf(x.z); u[3] = (short)f2bf(x.w);
    u[4] = (short)f2bf(y.x); u[5] = (short)f2bf(y.y);
    u[6] = (short)f2bf(y.z); u[7] = (short)f2bf(y.w);
    *(bf16x8*)&Aq[row * 512 + ((l ^ (row & 7)) << 3)] = u;
  }
  __syncthreads();  // the ONLY barrier

  f32x4 acc[3];
#pragma unroll
  for (int m = 0; m < 3; ++m) acc[m] = (f32x4){0.f, 0.f, 0.f, 0.f};

#pragma unroll
  for (int kk = 0; kk < 16; ++kk) {
    const int k16 = (kk + kb0) & 15;  // staggered K order
    const int aslot = (k16 * 4 + l4) ^ (l15 & 7);
    const bf16x8 af = *(const bf16x8*)&Aq[l15 * 512 + (aslot << 3)];
    const bf16x8 bfq =
        *(const bf16x8*)(Bfrag + ((size_t)(w * 16 + k16) * 64 + l) * 8);
    const bf16x8 bfk =
        *(const bf16x8*)(Bfrag + ((size_t)((4 + w) * 16 + k16) * 64 + l) * 8);
    const bf16x8 bfv =
        *(const bf16x8*)(Bfrag + ((size_t)((8 + w) * 16 + k16) * 64 + l) * 8);
    acc[0] = __builtin_amdgcn_mfma_f32_16x16x32_bf16(bfq, af, acc[0], 0, 0, 0);
    acc[1] = __builtin_amdgcn_mfma_f32_16x16x32_bf16(bfk, af, acc[1], 0, 0, 0);
    acc[2] = __builtin_amdgcn_mfma_f32_16x16x32_bf16(af, bfv, acc[2], 0, 0, 0);
  }

  // ---- Epilogue: bias + packed coalesced fragment stores.
  const int bidx = s0 >> 11;
  const size_t bbase = (size_t)bidx * (S * P);
  const int S0 = s0 & 2047;

  // q/k (swapped): lane holds p = w*16 + l4*4 + r, s = s0 + l15.
  const int p0 = w * 16 + l4 * 4;
  const float4 bq4 = *(const float4*)(bq + p0);
  const float4 bk4 = *(const float4*)(bk + p0);
  const size_t qkoff =
      bbase +
      ((((size_t)(S0 >> 4) * 2 + (p0 >> 5)) * 4 + ((p0 >> 3) & 3)) * 16 +
       l15) * 8 +
      (p0 & 7);
  s16x4 pq, pkk;
  pq[0] = (short)f2bf((acc[0][0] + bq4.x) * SCALE);
  pq[1] = (short)f2bf((acc[0][1] + bq4.y) * SCALE);
  pq[2] = (short)f2bf((acc[0][2] + bq4.z) * SCALE);
  pq[3] = (short)f2bf((acc[0][3] + bq4.w) * SCALE);
  pkk[0] = (short)f2bf(acc[1][0] + bk4.x);
  pkk[1] = (short)f2bf(acc[1][1] + bk4.y);
  pkk[2] = (short)f2bf(acc[1][2] + bk4.z);
  pkk[3] = (short)f2bf(acc[1][3] + bk4.w);
  *(s16x4*)(qfrag + qkoff) = pq;
  *(s16x4*)(kfrag + qkoff) = pkk;

  // v (normal): lane holds p = w*16 + l15, t = S0 + l4*4 + r.
  const float bbv = bv[w * 16 + l15];
  const int chv = ((S0 >> 3) + (l4 >> 1)) & 3;
  const size_t voff =
      bbase + ((((size_t)(S0 >> 5) * 4 + w) * 4 + chv) * 16 + l15) * 8 +
      (l4 & 1) * 4;
  s16x4 pv;
  pv[0] = (short)f2bf(acc[2][0] + bbv);
  pv[1] = (short)f2bf(acc[2][1] + bbv);
  pv[2] = (short)f2bf(acc[2][2] + bbv);
  pv[3] = (short)f2bf(acc[2][3] + bbv);
  *(s16x4*)(vfrag + voff) = pv;
}

// ---------------------------------------------------------------------------
// Kernel 2: flash attention + fused output projection.
// Grid 512 x 1024 thr (16 waves).  Block = 32 q-rows of one batch
// (blk&7=batch -> XCD L2 pinning).  LDS ~70 KB -> 2 blocks/CU; with the
// allocator's default 64 VGPR that is 8 waves/SIMD (round-7 evidence:
// structure reaches 69% occupancy; round-7's waves_per_eu(8) hint cut
// VGPR to 32 and spilled -- hint removed this round).
// Wave w = th (0..15) owns t in [th*128, th*128+128): 2 windows of 64 t,
// window order staggered by qt&1.  e-tile SINGLE-buffered 4 KB/wave.
// QK^T operand-SWAPPED: scores D[t][q] (lane: t-run of 4, q=l15) -> exp
// packs into one s16x4 store per n-tile into the verified layout:
//   elem(q, t) at byte  st*2048 + q*128 + ((t*2) ^ ((q&7)<<4))
// PV reads it back with the verified swizzled ds_read_b128:
//   ae at byte          st*2048 + l15*128 + ((hf*64 + l4*16) ^ ((l15&7)<<4))
// Epilogue: two p-phase combine over pacc [16][32][32] f32 (64 KB, aliases
// e), then wnorm [32][64] bf16 -> fused Wo projection.  (Round-7-verified.)
// ---------------------------------------------------------------------------
__global__ __launch_bounds__(1024) void attn_fused(
    const unsigned short* __restrict__ qfrag,
    const unsigned short* __restrict__ kfrag,
    const unsigned short* __restrict__ vfrag,
    const unsigned short* __restrict__ Wofrag, const float* __restrict__ bo,
    float* __restrict__ out) {
  // smem: main loop e = 16 waves x 4 KB = 64 KB at offset 0;
  //       epilogue pacc [16][32][32] f32 = 64 KB aliases offset 0;
  //       wnorm [32][64] bf16 = 4 KB at offset 65536.  Total 68 KB + l_s.
  __shared__ __align__(16) unsigned char smem[69632];
  __shared__ float l_s[16][32];

  const int tid = threadIdx.x;
  const int w = tid >> 6;   // th 0..15
  const int lane = tid & 63;
  const int l15 = lane & 15;
  const int l4 = lane >> 4;

  const int blk = blockIdx.x;  // 0..511
  const int b = blk & 7;
  const int qt = blk >> 3;     // 0..63
  const int s0 = qt * 32;
  const int wst = qt & 1;      // window-phase stagger

  const size_t bbase = (size_t)b * (S * P);
  const unsigned short* qf = qfrag + bbase;
  const unsigned short* kf = kfrag + bbase;
  const unsigned short* vf = vfrag + bbase;

  unsigned char* e_w = smem + w * 4096;  // 4 KB/wave, single buffer
  const int xm = (l15 & 7) << 4;         // q-row XOR swizzle mask (bytes)

  // q A-fragments: tiles qt*2 + st.
  bf16x8 aq[2][2];
#pragma unroll
  for (int st = 0; st < 2; ++st)
#pragma unroll
    for (int h = 0; h < 2; ++h)
      aq[st][h] =
          *(const bf16x8*)(qf +
                           ((size_t)((qt * 2 + st) * 2 + h) * 64 + lane) * 8);

  f32x4 acc[2][4];
#pragma unroll
  for (int st = 0; st < 2; ++st)
#pragma unroll
    for (int pc = 0; pc < 4; ++pc) acc[st][pc] = (f32x4){0.f, 0.f, 0.f, 0.f};
  float lpart[2] = {0.f, 0.f};

  for (int win = 0; win < 2; ++win) {
    const int wi = (win + wst) & 1;     // staggered window
    const int t0 = w * 128 + wi * 64;
    unsigned char* epb = e_w;           // single buffer

    // Two 32-t half-windows; runtime loop caps register liveness.
#pragma unroll 1
    for (int hf = 0; hf < 2; ++hf) {
      // k fragments for this half (4 coalesced 1 KB loads).
      bf16x8 bkh[2][2];
#pragma unroll
      for (int j = 0; j < 2; ++j)
#pragma unroll
        for (int h = 0; h < 2; ++h)
          bkh[j][h] =
              *(const bf16x8*)(kf + ((size_t)(((t0 >> 4) + hf * 2 + j) * 2 +
                                              h) * 64 + lane) * 8);

      // QK^T + exp/pack/store per subtile.  t = (hf*2+j)*16 + l4*4 + r.
#pragma unroll
      for (int st = 0; st < 2; ++st) {
        f32x4 sc[2];
#pragma unroll
        for (int j = 0; j < 2; ++j) {
          f32x4 c = (f32x4){0.f, 0.f, 0.f, 0.f};
          c = __builtin_amdgcn_mfma_f32_16x16x32_bf16(bkh[j][0], aq[st][0], c,
                                                      0, 0, 0);
          sc[j] = __builtin_amdgcn_mfma_f32_16x16x32_bf16(bkh[j][1], aq[st][1],
                                                          c, 0, 0, 0);
        }
#pragma unroll
        for (int j = 0; j < 2; ++j) {
          s16x4 pk;
#pragma unroll
          for (int r = 0; r < 4; ++r) pk[r] = (short)f2bf(__expf(sc[j][r]));
#pragma unroll
          for (int r = 0; r < 4; ++r)
            lpart[st] += bf2f((unsigned short)pk[r]);
          *(s16x4*)(epb + st * 2048 + l15 * 128 +
                    (((hf * 2 + j) * 32 + l4 * 8) ^ xm)) = pk;
        }
      }

      // v fragments for this half (4 coalesced 1 KB loads).
      bf16x8 bvh[4];
#pragma unroll
      for (int pc = 0; pc < 4; ++pc)
        bvh[pc] =
            *(const bf16x8*)(vf + ((size_t)(((t0 >> 5) + hf) * 4 + pc) * 64 +
                                   lane) * 8);

      // PV for this half (same-wave DS ordering makes stores visible).
#pragma unroll
      for (int st = 0; st < 2; ++st) {
        const bf16x8 ae = *(const bf16x8*)(epb + st * 2048 + l15 * 128 +
                                           ((hf * 64 + l4 * 16) ^ xm));
#pragma unroll
        for (int pc = 0; pc < 4; ++pc)
          acc[st][pc] = __builtin_amdgcn_mfma_f32_16x16x32_bf16(
              ae, bvh[pc], acc[st][pc], 0, 0, 0);
      }
    }
  }

  // ---- Row-sums: intra-lane over t, then across the 4 l4-groups.
#pragma unroll
  for (int st = 0; st < 2; ++st) {
    float v = lpart[st];
    v += __shfl_xor(v, 16, 64);
    v += __shfl_xor(v, 32, 64);
    if (l4 == 0) l_s[w][st * 16 + l15] = v;
  }

  __syncthreads();  // all waves done with e-tiles before pacc aliases them

  float* pacc = (float*)smem;                               // [16][32][32]
  unsigned short* wnorm = (unsigned short*)(smem + 65536);  // [32][64]

  // Per-lane combine coordinates (fixed across phases).
  const int crow = (w & 7) * 4 + l4;               // 0..31
  const int prel = (w >> 3) * 16 + l15;            // 0..31 within p-half
  const int rc = (((w >> 3) ^ (w & 1)) << 4) + l15;  // swizzled read col
  float ls = 0.f;
#pragma unroll
  for (int s2 = 0; s2 < 16; ++s2) ls += l_s[s2][crow];
  const float inv = 1.f / ls;

#pragma unroll 1
  for (int ph = 0; ph < 2; ++ph) {
    // Dump: wave w writes acc for pc = ph*2 + {0,1}.
#pragma unroll
    for (int st = 0; st < 2; ++st)
#pragma unroll
      for (int pcx = 0; pcx < 2; ++pcx) {
        const int pc = ph * 2 + pcx;
        const int cs = ((pcx ^ (l4 & 1)) << 4) + l15;  // 2-way banks
#pragma unroll
        for (int r = 0; r < 4; ++r) {
          const int row = st * 16 + l4 * 4 + r;
          pacc[(w * 32 + row) * 32 + cs] = acc[st][pc][r];
        }
      }
    __syncthreads();

    // Combine: one (row, col) per lane, summed over all 16 sources.
    float s = 0.f;
#pragma unroll
    for (int s2 = 0; s2 < 16; ++s2) s += pacc[(s2 * 32 + crow) * 32 + rc];
    wnorm[crow * 64 + ph * 32 + prel] = f2bf(s * inv);
    __syncthreads();  // combine reads done before next dump / before proj
  }

  // ---- Fused output projection: 16 waves = (2 row-subtiles) x (8 col-64s).
  const int sub = w & 1;    // 16-row subtile
  const int chq = w >> 1;   // 64-col group (0..7)
  const bf16x8 a0 = *(const bf16x8*)&wnorm[(sub * 16 + l15) * 64 + l4 * 8];
  const bf16x8 a1 =
      *(const bf16x8*)&wnorm[(sub * 16 + l15) * 64 + 32 + l4 * 8];
  const size_t orow0 = (size_t)b * S + s0 + sub * 16;
#pragma unroll
  for (int ct = 0; ct < 4; ++ct) {
    const int ctg = chq * 4 + ((ct + (blk & 3)) & 3);  // staggered Wo tiles
    const bf16x8 b0 =
        *(const bf16x8*)(Wofrag + ((size_t)(ctg * 2 + 0) * 64 + lane) * 8);
    const bf16x8 b1 =
        *(const bf16x8*)(Wofrag + ((size_t)(ctg * 2 + 1) * 64 + lane) * 8);
    f32x4 c = (f32x4){0.f, 0.f, 0.f, 0.f};
    c = __builtin_amdgcn_mfma_f32_16x16x32_bf16(a0, b0, c, 0, 0, 0);
    c = __builtin_amdgcn_mfma_f32_16x16x32_bf16(a1, b1, c, 0, 0, 0);
    const int col = ctg * 16 + l15;
    const float bb = bo[col];
#pragma unroll
    for (int r = 0; r < 4; ++r)
      out[(orow0 + l4 * 4 + r) * D + col] = c[r] + bb;
  }
}

// ---------------------------------------------------------------------------
extern "C" void kernel_launch(void* const* d_in, const int* in_sizes, int n_in,
                              void* d_out, int out_size, void* d_ws,
                              size_t ws_size, hipStream_t stream) {
  const float* query = (const float*)d_in[0];
  // d_in[1] = attention_mask: unused (per-row additive constant -> softmax no-op)
  const float* Wq = (const float*)d_in[2];
  const float* bq = (const float*)d_in[3];
  const float* Wk = (const float*)d_in[4];
  const float* bk = (const float*)d_in[5];
  const float* Wv = (const float*)d_in[6];
  const float* bv = (const float*)d_in[7];
  const float* Wo = (const float*)d_in[8];
  const float* bo = (const float*)d_in[9];
  float* out = (float*)d_out;

  // Workspace (bf16): qfrag 2MB | kfrag 2MB | vfrag 2MB | Bfrag 192KB | Wofrag 64KB
  const size_t proj = (size_t)B * S * P;  // 1,048,576
  unsigned short* qfr = (unsigned short*)d_ws;
  unsigned short* kfr = qfr + proj;
  unsigned short* vfr = kfr + proj;
  unsigned short* Bfrag = vfr + proj;
  unsigned short* Wofrag = Bfrag + 192 * 512;

  prep_w<<<384, 256, 0, stream>>>(Wq, Wk, Wv, Wo, Bfrag, Wofrag);
  qkv_mfma<<<1024, 256, 0, stream>>>(query, Bfrag, bq, bk, bv, qfr, kfr, vfr);
  attn_fused<<<512, 1024, 0, stream>>>(qfr, kfr, vfr, Wofrag, bo, out);
}

// Round 9
// 145.327 us; speedup vs baseline: 1.4650x; 1.0096x over previous
//
#include <hip/hip_runtime.h>
#include <hip/hip_bf16.h>
#include <math.h>

// Problem constants (from reference)
constexpr int B = 8;
constexpr int S = 2048;
constexpr int D = 512;
constexpr int P = 64;
constexpr float SCALE = 0.125f;  // 1/sqrt(P)

typedef short bf16x8 __attribute__((ext_vector_type(8)));
typedef short s16x4 __attribute__((ext_vector_type(4)));
typedef float f32x4 __attribute__((ext_vector_type(4)));

__device__ __forceinline__ unsigned short f2bf(float x) {
  __hip_bfloat16 h = __float2bfloat16(x);
  return __builtin_bit_cast(unsigned short, h);
}
__device__ __forceinline__ float bf2f(unsigned short u) {
  unsigned int v = (unsigned int)u << 16;
  return __builtin_bit_cast(float, v);
}

// ===========================================================================
// Fragment-packed layouts: every MFMA fragment is a contiguous 64-lane x 16 B
// = 1 KB lane-ordered chunk -> one coalesced dwordx4 per consumer load.
//  Bfrag  [12 ntile][16 k16][64 lane][8]   : WqWkWv cat (192 cols, K=512)
//  Wofrag [32 ct][2 h][64 lane][8]         : Wo (512 cols, K=64)
//  qfrag/kfrag [b][128 tile][2 h][64][8]   : tile=16 rows, h=K-half
//  vfrag  [b][64 tb][4 pc][64][8]          : tb=32 t's, pc=16 p's (t = K dim)
// Round-9 change (single variable vs round 8).  Allocator dose-response now
// mapped on this 1024-thread body:
//   waves_per_eu(8) -> 32 VGPR (r7, spill explosion)
//   none            -> 56 VGPR (r8, spill: 48 persistent regs leave 8)
//   waves_per_eu(4,4)-> 64 VGPR (r4/5/6, ZERO spill with half-window body)
// The grid-512 / 70 KB structure is HW-verified (passed r7/r8) and reaches
// 69% occupancy when not spilling.  waves_per_eu is an ALLOCATION hint, not
// a runtime cap: with 64 VGPR + 70 KB LDS the HW can still run 8 waves/SIMD.
//  * attn: round-8 source + amdgpu_waves_per_eu(4,4) restored.  Nothing else.
// ===========================================================================

// ---------------------------------------------------------------------------
// Kernel 0: weight prep -> fragment-packed bf16.
// ---------------------------------------------------------------------------
__global__ __launch_bounds__(256) void prep_w(
    const float* __restrict__ Wq, const float* __restrict__ Wk,
    const float* __restrict__ Wv, const float* __restrict__ Wo,
    unsigned short* __restrict__ Bfrag, unsigned short* __restrict__ Wofrag) {
  const int i = blockIdx.x * 256 + threadIdx.x;
  if (i < 192 * 512) {
    const int d = i / 192;        // K index 0..511
    const int n = i - d * 192;    // output col 0..191
    const float* W = (n < 64) ? Wq : (n < 128) ? Wk : Wv;
    const float val = W[d * 64 + (n & 63)];
    const int nt = n >> 4, l15 = n & 15;
    const int k16 = d >> 5, l4 = (d >> 3) & 3, j = d & 7;
    Bfrag[(((nt * 16 + k16) * 4 + l4) * 16 + l15) * 8 + j] = f2bf(val);
  }
  if (i < 64 * 512) {
    const int k = i >> 9;   // 0..63   (P dim)
    const int n = i & 511;  // 0..511  (D dim)
    const float val = Wo[k * 512 + n];
    const int ct = n >> 4, l15 = n & 15;
    const int h = k >> 5, l4 = (k >> 3) & 3, j = k & 7;
    Wofrag[(((ct * 2 + h) * 4 + l4) * 16 + l15) * 8 + j] = f2bf(val);
  }
}

// ---------------------------------------------------------------------------
// Kernel 1: QKV projection (round-5 version).  Grid 1024 x 256.
// Block = 16 rows x 192 cols; wave w owns n-tiles {w (q), 4+w (k), 8+w (v)}.
// q/k use OPERAND-SWAPPED MFMA -> C[p][s]: lane holds a p-run of 4 -> one
// packed 8B store per matrix.  v stays C[s][p].  K-loop staggered; 1 barrier.
// ---------------------------------------------------------------------------
__global__ __launch_bounds__(256)
__attribute__((amdgpu_waves_per_eu(4, 4))) void qkv_mfma(
    const float* __restrict__ query, const unsigned short* __restrict__ Bfrag,
    const float* __restrict__ bq, const float* __restrict__ bk,
    const float* __restrict__ bv, unsigned short* __restrict__ qfrag,
    unsigned short* __restrict__ kfrag, unsigned short* __restrict__ vfrag) {
  __shared__ __align__(16) unsigned short Aq[16 * 512];  // 16 KB

  const int tid = threadIdx.x;
  const int w = tid >> 6;
  const int l = tid & 63;
  const int l15 = l & 15;
  const int l4 = l >> 4;
  const int s0 = blockIdx.x * 16;
  const int kb0 = blockIdx.x & 15;  // K-phase stagger

  // ---- Prologue: 16 query rows fp32 -> bf16 swizzled LDS tile.
  const float* qsrc = query + (size_t)s0 * D;
#pragma unroll
  for (int step = 0; step < 4; ++step) {
    const int row = step * 4 + w;  // wave-uniform
    const float* pf = qsrc + row * D + l * 8;
    const float4 x = *(const float4*)pf;
    const float4 y = *(const float4*)(pf + 4);
    bf16x8 u;
    u[0] = (short)f2bf(x.x); u[1] = (short)f2bf(x.y);
    u[2] = (short)f2bf(x.z); u[3] = (short)f2bf(x.w);
    u[4] = (short)f2bf(y.x); u[5] = (short)f2bf(y.y);
    u[6] = (short)f2bf(y.z); u[7] = (short)f2bf(y.w);
    *(bf16x8*)&Aq[row * 512 + ((l ^ (row & 7)) << 3)] = u;
  }
  __syncthreads();  // the ONLY barrier

  f32x4 acc[3];
#pragma unroll
  for (int m = 0; m < 3; ++m) acc[m] = (f32x4){0.f, 0.f, 0.f, 0.f};

#pragma unroll
  for (int kk = 0; kk < 16; ++kk) {
    const int k16 = (kk + kb0) & 15;  // staggered K order
    const int aslot = (k16 * 4 + l4) ^ (l15 & 7);
    const bf16x8 af = *(const bf16x8*)&Aq[l15 * 512 + (aslot << 3)];
    const bf16x8 bfq =
        *(const bf16x8*)(Bfrag + ((size_t)(w * 16 + k16) * 64 + l) * 8);
    const bf16x8 bfk =
        *(const bf16x8*)(Bfrag + ((size_t)((4 + w) * 16 + k16) * 64 + l) * 8);
    const bf16x8 bfv =
        *(const bf16x8*)(Bfrag + ((size_t)((8 + w) * 16 + k16) * 64 + l) * 8);
    acc[0] = __builtin_amdgcn_mfma_f32_16x16x32_bf16(bfq, af, acc[0], 0, 0, 0);
    acc[1] = __builtin_amdgcn_mfma_f32_16x16x32_bf16(bfk, af, acc[1], 0, 0, 0);
    acc[2] = __builtin_amdgcn_mfma_f32_16x16x32_bf16(af, bfv, acc[2], 0, 0, 0);
  }

  // ---- Epilogue: bias + packed coalesced fragment stores.
  const int bidx = s0 >> 11;
  const size_t bbase = (size_t)bidx * (S * P);
  const int S0 = s0 & 2047;

  // q/k (swapped): lane holds p = w*16 + l4*4 + r, s = s0 + l15.
  const int p0 = w * 16 + l4 * 4;
  const float4 bq4 = *(const float4*)(bq + p0);
  const float4 bk4 = *(const float4*)(bk + p0);
  const size_t qkoff =
      bbase +
      ((((size_t)(S0 >> 4) * 2 + (p0 >> 5)) * 4 + ((p0 >> 3) & 3)) * 16 +
       l15) * 8 +
      (p0 & 7);
  s16x4 pq, pkk;
  pq[0] = (short)f2bf((acc[0][0] + bq4.x) * SCALE);
  pq[1] = (short)f2bf((acc[0][1] + bq4.y) * SCALE);
  pq[2] = (short)f2bf((acc[0][2] + bq4.z) * SCALE);
  pq[3] = (short)f2bf((acc[0][3] + bq4.w) * SCALE);
  pkk[0] = (short)f2bf(acc[1][0] + bk4.x);
  pkk[1] = (short)f2bf(acc[1][1] + bk4.y);
  pkk[2] = (short)f2bf(acc[1][2] + bk4.z);
  pkk[3] = (short)f2bf(acc[1][3] + bk4.w);
  *(s16x4*)(qfrag + qkoff) = pq;
  *(s16x4*)(kfrag + qkoff) = pkk;

  // v (normal): lane holds p = w*16 + l15, t = S0 + l4*4 + r.
  const float bbv = bv[w * 16 + l15];
  const int chv = ((S0 >> 3) + (l4 >> 1)) & 3;
  const size_t voff =
      bbase + ((((size_t)(S0 >> 5) * 4 + w) * 4 + chv) * 16 + l15) * 8 +
      (l4 & 1) * 4;
  s16x4 pv;
  pv[0] = (short)f2bf(acc[2][0] + bbv);
  pv[1] = (short)f2bf(acc[2][1] + bbv);
  pv[2] = (short)f2bf(acc[2][2] + bbv);
  pv[3] = (short)f2bf(acc[2][3] + bbv);
  *(s16x4*)(vfrag + voff) = pv;
}

// ---------------------------------------------------------------------------
// Kernel 2: flash attention + fused output projection.
// Grid 512 x 1024 thr (16 waves).  Block = 32 q-rows of one batch
// (blk&7=batch -> XCD L2 pinning).  LDS ~70 KB -> 2 blocks/CU.
// waves_per_eu(4,4): the allocation recipe that yields 64 VGPR + zero spill
// on this body (r4/5/6); runtime occupancy can still reach 8 waves/SIMD
// since 64 VGPR x 8 = 512 fits the register file and LDS fits 2 blocks.
// Wave w = th (0..15) owns t in [th*128, th*128+128): 2 windows of 64 t,
// window order staggered by qt&1.  e-tile SINGLE-buffered 4 KB/wave.
// QK^T operand-SWAPPED: scores D[t][q] (lane: t-run of 4, q=l15) -> exp
// packs into one s16x4 store per n-tile into the verified layout:
//   elem(q, t) at byte  st*2048 + q*128 + ((t*2) ^ ((q&7)<<4))
// PV reads it back with the verified swizzled ds_read_b128:
//   ae at byte          st*2048 + l15*128 + ((hf*64 + l4*16) ^ ((l15&7)<<4))
// Epilogue: two p-phase combine over pacc [16][32][32] f32 (64 KB, aliases
// e), then wnorm [32][64] bf16 -> fused Wo projection.  (HW-verified r7/r8.)
// ---------------------------------------------------------------------------
__global__ __launch_bounds__(1024)
__attribute__((amdgpu_waves_per_eu(4, 4))) void attn_fused(
    const unsigned short* __restrict__ qfrag,
    const unsigned short* __restrict__ kfrag,
    const unsigned short* __restrict__ vfrag,
    const unsigned short* __restrict__ Wofrag, const float* __restrict__ bo,
    float* __restrict__ out) {
  // smem: main loop e = 16 waves x 4 KB = 64 KB at offset 0;
  //       epilogue pacc [16][32][32] f32 = 64 KB aliases offset 0;
  //       wnorm [32][64] bf16 = 4 KB at offset 65536.  Total 68 KB + l_s.
  __shared__ __align__(16) unsigned char smem[69632];
  __shared__ float l_s[16][32];

  const int tid = threadIdx.x;
  const int w = tid >> 6;   // th 0..15
  const int lane = tid & 63;
  const int l15 = lane & 15;
  const int l4 = lane >> 4;

  const int blk = blockIdx.x;  // 0..511
  const int b = blk & 7;
  const int qt = blk >> 3;     // 0..63
  const int s0 = qt * 32;
  const int wst = qt & 1;      // window-phase stagger

  const size_t bbase = (size_t)b * (S * P);
  const unsigned short* qf = qfrag + bbase;
  const unsigned short* kf = kfrag + bbase;
  const unsigned short* vf = vfrag + bbase;

  unsigned char* e_w = smem + w * 4096;  // 4 KB/wave, single buffer
  const int xm = (l15 & 7) << 4;         // q-row XOR swizzle mask (bytes)

  // q A-fragments: tiles qt*2 + st.
  bf16x8 aq[2][2];
#pragma unroll
  for (int st = 0; st < 2; ++st)
#pragma unroll
    for (int h = 0; h < 2; ++h)
      aq[st][h] =
          *(const bf16x8*)(qf +
                           ((size_t)((qt * 2 + st) * 2 + h) * 64 + lane) * 8);

  f32x4 acc[2][4];
#pragma unroll
  for (int st = 0; st < 2; ++st)
#pragma unroll
    for (int pc = 0; pc < 4; ++pc) acc[st][pc] = (f32x4){0.f, 0.f, 0.f, 0.f};
  float lpart[2] = {0.f, 0.f};

  for (int win = 0; win < 2; ++win) {
    const int wi = (win + wst) & 1;     // staggered window
    const int t0 = w * 128 + wi * 64;
    unsigned char* epb = e_w;           // single buffer

    // Two 32-t half-windows; runtime loop caps register liveness.
#pragma unroll 1
    for (int hf = 0; hf < 2; ++hf) {
      // k fragments for this half (4 coalesced 1 KB loads).
      bf16x8 bkh[2][2];
#pragma unroll
      for (int j = 0; j < 2; ++j)
#pragma unroll
        for (int h = 0; h < 2; ++h)
          bkh[j][h] =
              *(const bf16x8*)(kf + ((size_t)(((t0 >> 4) + hf * 2 + j) * 2 +
                                              h) * 64 + lane) * 8);

      // QK^T + exp/pack/store per subtile.  t = (hf*2+j)*16 + l4*4 + r.
#pragma unroll
      for (int st = 0; st < 2; ++st) {
        f32x4 sc[2];
#pragma unroll
        for (int j = 0; j < 2; ++j) {
          f32x4 c = (f32x4){0.f, 0.f, 0.f, 0.f};
          c = __builtin_amdgcn_mfma_f32_16x16x32_bf16(bkh[j][0], aq[st][0], c,
                                                      0, 0, 0);
          sc[j] = __builtin_amdgcn_mfma_f32_16x16x32_bf16(bkh[j][1], aq[st][1],
                                                          c, 0, 0, 0);
        }
#pragma unroll
        for (int j = 0; j < 2; ++j) {
          s16x4 pk;
#pragma unroll
          for (int r = 0; r < 4; ++r) pk[r] = (short)f2bf(__expf(sc[j][r]));
#pragma unroll
          for (int r = 0; r < 4; ++r)
            lpart[st] += bf2f((unsigned short)pk[r]);
          *(s16x4*)(epb + st * 2048 + l15 * 128 +
                    (((hf * 2 + j) * 32 + l4 * 8) ^ xm)) = pk;
        }
      }

      // v fragments for this half (4 coalesced 1 KB loads).
      bf16x8 bvh[4];
#pragma unroll
      for (int pc = 0; pc < 4; ++pc)
        bvh[pc] =
            *(const bf16x8*)(vf + ((size_t)(((t0 >> 5) + hf) * 4 + pc) * 64 +
                                   lane) * 8);

      // PV for this half (same-wave DS ordering makes stores visible).
#pragma unroll
      for (int st = 0; st < 2; ++st) {
        const bf16x8 ae = *(const bf16x8*)(epb + st * 2048 + l15 * 128 +
                                           ((hf * 64 + l4 * 16) ^ xm));
#pragma unroll
        for (int pc = 0; pc < 4; ++pc)
          acc[st][pc] = __builtin_amdgcn_mfma_f32_16x16x32_bf16(
              ae, bvh[pc], acc[st][pc], 0, 0, 0);
      }
    }
  }

  // ---- Row-sums: intra-lane over t, then across the 4 l4-groups.
#pragma unroll
  for (int st = 0; st < 2; ++st) {
    float v = lpart[st];
    v += __shfl_xor(v, 16, 64);
    v += __shfl_xor(v, 32, 64);
    if (l4 == 0) l_s[w][st * 16 + l15] = v;
  }

  __syncthreads();  // all waves done with e-tiles before pacc aliases them

  float* pacc = (float*)smem;                               // [16][32][32]
  unsigned short* wnorm = (unsigned short*)(smem + 65536);  // [32][64]

  // Per-lane combine coordinates (fixed across phases).
  const int crow = (w & 7) * 4 + l4;               // 0..31
  const int prel = (w >> 3) * 16 + l15;            // 0..31 within p-half
  const int rc = (((w >> 3) ^ (w & 1)) << 4) + l15;  // swizzled read col
  float ls = 0.f;
#pragma unroll
  for (int s2 = 0; s2 < 16; ++s2) ls += l_s[s2][crow];
  const float inv = 1.f / ls;

#pragma unroll 1
  for (int ph = 0; ph < 2; ++ph) {
    // Dump: wave w writes acc for pc = ph*2 + {0,1}.
#pragma unroll
    for (int st = 0; st < 2; ++st)
#pragma unroll
      for (int pcx = 0; pcx < 2; ++pcx) {
        const int pc = ph * 2 + pcx;
        const int cs = ((pcx ^ (l4 & 1)) << 4) + l15;  // 2-way banks
#pragma unroll
        for (int r = 0; r < 4; ++r) {
          const int row = st * 16 + l4 * 4 + r;
          pacc[(w * 32 + row) * 32 + cs] = acc[st][pc][r];
        }
      }
    __syncthreads();

    // Combine: one (row, col) per lane, summed over all 16 sources.
    float s = 0.f;
#pragma unroll
    for (int s2 = 0; s2 < 16; ++s2) s += pacc[(s2 * 32 + crow) * 32 + rc];
    wnorm[crow * 64 + ph * 32 + prel] = f2bf(s * inv);
    __syncthreads();  // combine reads done before next dump / before proj
  }

  // ---- Fused output projection: 16 waves = (2 row-subtiles) x (8 col-64s).
  const int sub = w & 1;    // 16-row subtile
  const int chq = w >> 1;   // 64-col group (0..7)
  const bf16x8 a0 = *(const bf16x8*)&wnorm[(sub * 16 + l15) * 64 + l4 * 8];
  const bf16x8 a1 =
      *(const bf16x8*)&wnorm[(sub * 16 + l15) * 64 + 32 + l4 * 8];
  const size_t orow0 = (size_t)b * S + s0 + sub * 16;
#pragma unroll
  for (int ct = 0; ct < 4; ++ct) {
    const int ctg = chq * 4 + ((ct + (blk & 3)) & 3);  // staggered Wo tiles
    const bf16x8 b0 =
        *(const bf16x8*)(Wofrag + ((size_t)(ctg * 2 + 0) * 64 + lane) * 8);
    const bf16x8 b1 =
        *(const bf16x8*)(Wofrag + ((size_t)(ctg * 2 + 1) * 64 + lane) * 8);
    f32x4 c = (f32x4){0.f, 0.f, 0.f, 0.f};
    c = __builtin_amdgcn_mfma_f32_16x16x32_bf16(a0, b0, c, 0, 0, 0);
    c = __builtin_amdgcn_mfma_f32_16x16x32_bf16(a1, b1, c, 0, 0, 0);
    const int col = ctg * 16 + l15;
    const float bb = bo[col];
#pragma unroll
    for (int r = 0; r < 4; ++r)
      out[(orow0 + l4 * 4 + r) * D + col] = c[r] + bb;
  }
}

// ---------------------------------------------------------------------------
extern "C" void kernel_launch(void* const* d_in, const int* in_sizes, int n_in,
                              void* d_out, int out_size, void* d_ws,
                              size_t ws_size, hipStream_t stream) {
  const float* query = (const float*)d_in[0];
  // d_in[1] = attention_mask: unused (per-row additive constant -> softmax no-op)
  const float* Wq = (const float*)d_in[2];
  const float* bq = (const float*)d_in[3];
  const float* Wk = (const float*)d_in[4];
  const float* bk = (const float*)d_in[5];
  const float* Wv = (const float*)d_in[6];
  const float* bv = (const float*)d_in[7];
  const float* Wo = (const float*)d_in[8];
  const float* bo = (const float*)d_in[9];
  float* out = (float*)d_out;

  // Workspace (bf16): qfrag 2MB | kfrag 2MB | vfrag 2MB | Bfrag 192KB | Wofrag 64KB
  const size_t proj = (size_t)B * S * P;  // 1,048,576
  unsigned short* qfr = (unsigned short*)d_ws;
  unsigned short* kfr = qfr + proj;
  unsigned short* vfr = kfr + proj;
  unsigned short* Bfrag = vfr + proj;
  unsigned short* Wofrag = Bfrag + 192 * 512;

  prep_w<<<384, 256, 0, stream>>>(Wq, Wk, Wv, Wo, Bfrag, Wofrag);
  qkv_mfma<<<1024, 256, 0, stream>>>(query, Bfrag, bq, bk, bv, qfr, kfr, vfr);
  attn_fused<<<512, 1024, 0, stream>>>(qfr, kfr, vfr, Wofrag, bo, out);
}

// Round 10
// 122.287 us; speedup vs baseline: 1.7410x; 1.1884x over previous
//
#include <hip/hip_runtime.h>
#include <hip/hip_bf16.h>
#include <math.h>

// Problem constants (from reference)
constexpr int B = 8;
constexpr int S = 2048;
constexpr int D = 512;
constexpr int P = 64;
constexpr float SCALE = 0.125f;  // 1/sqrt(P)

typedef short bf16x8 __attribute__((ext_vector_type(8)));
typedef short s16x4 __attribute__((ext_vector_type(4)));
typedef float f32x4 __attribute__((ext_vector_type(4)));

__device__ __forceinline__ unsigned short f2bf(float x) {
  __hip_bfloat16 h = __float2bfloat16(x);
  return __builtin_bit_cast(unsigned short, h);
}
__device__ __forceinline__ float bf2f(unsigned short u) {
  unsigned int v = (unsigned int)u << 16;
  return __builtin_bit_cast(float, v);
}

// ===========================================================================
// Fragment-packed layouts: every MFMA fragment is a contiguous 64-lane x 16 B
// = 1 KB lane-ordered chunk -> one coalesced dwordx4 per consumer load.
//  Bfrag  [12 ntile][16 k16][64 lane][8]   : WqWkWv cat (192 cols, K=512)
//  Wofrag [32 ct][2 h][64 lane][8]         : Wo (512 cols, K=64)
//  qfrag/kfrag [b][128 tile][2 h][64][8]   : tile=16 rows, h=K-half
//  vfrag  [b][64 tb][4 pc][64][8]          : tb=32 t's, pc=16 p's (t = K dim)
// Round-10: REVERT to the round-5 configuration (best measured: 124.1 us).
// The grid-512 occupancy arc (r7-r9) is closed: the allocator pins this
// 1024-thread body at 56 VGPR regardless of hints (r7:32, r8:56, r9:56),
// leaving ~62 MB spill.  Revised cost model across all rounds:
//   total ~= 100us fixed (prep + qkv + harness fills + launches) + attn_warm
//   (r2:157~=100+57, r8:147~=100+47.5, r5:124 => attn ~24us, qkv ~10-15us).
// Single addition vs round 5: s_setprio(1/0) around the MFMA clusters in
// attn's barrier-free main loop (T5: helps attn when independent waves sit
// at different phases; +4-7% measured on attn-like kernels).
// ===========================================================================

// ---------------------------------------------------------------------------
// Kernel 0: weight prep -> fragment-packed bf16.
// ---------------------------------------------------------------------------
__global__ __launch_bounds__(256) void prep_w(
    const float* __restrict__ Wq, const float* __restrict__ Wk,
    const float* __restrict__ Wv, const float* __restrict__ Wo,
    unsigned short* __restrict__ Bfrag, unsigned short* __restrict__ Wofrag) {
  const int i = blockIdx.x * 256 + threadIdx.x;
  if (i < 192 * 512) {
    const int d = i / 192;        // K index 0..511
    const int n = i - d * 192;    // output col 0..191
    const float* W = (n < 64) ? Wq : (n < 128) ? Wk : Wv;
    const float val = W[d * 64 + (n & 63)];
    const int nt = n >> 4, l15 = n & 15;
    const int k16 = d >> 5, l4 = (d >> 3) & 3, j = d & 7;
    Bfrag[(((nt * 16 + k16) * 4 + l4) * 16 + l15) * 8 + j] = f2bf(val);
  }
  if (i < 64 * 512) {
    const int k = i >> 9;   // 0..63   (P dim)
    const int n = i & 511;  // 0..511  (D dim)
    const float val = Wo[k * 512 + n];
    const int ct = n >> 4, l15 = n & 15;
    const int h = k >> 5, l4 = (k >> 3) & 3, j = k & 7;
    Wofrag[(((ct * 2 + h) * 4 + l4) * 16 + l15) * 8 + j] = f2bf(val);
  }
}

// ---------------------------------------------------------------------------
// Kernel 1: QKV projection (round-5 version).  Grid 1024 x 256.
// Block = 16 rows x 192 cols; wave w owns n-tiles {w (q), 4+w (k), 8+w (v)}.
// q/k use OPERAND-SWAPPED MFMA -> C[p][s]: lane holds a p-run of 4 -> one
// packed 8B store per matrix.  v stays C[s][p].  K-loop staggered; 1 barrier.
// ---------------------------------------------------------------------------
__global__ __launch_bounds__(256)
__attribute__((amdgpu_waves_per_eu(4, 4))) void qkv_mfma(
    const float* __restrict__ query, const unsigned short* __restrict__ Bfrag,
    const float* __restrict__ bq, const float* __restrict__ bk,
    const float* __restrict__ bv, unsigned short* __restrict__ qfrag,
    unsigned short* __restrict__ kfrag, unsigned short* __restrict__ vfrag) {
  __shared__ __align__(16) unsigned short Aq[16 * 512];  // 16 KB

  const int tid = threadIdx.x;
  const int w = tid >> 6;
  const int l = tid & 63;
  const int l15 = l & 15;
  const int l4 = l >> 4;
  const int s0 = blockIdx.x * 16;
  const int kb0 = blockIdx.x & 15;  // K-phase stagger

  // ---- Prologue: 16 query rows fp32 -> bf16 swizzled LDS tile.
  const float* qsrc = query + (size_t)s0 * D;
#pragma unroll
  for (int step = 0; step < 4; ++step) {
    const int row = step * 4 + w;  // wave-uniform
    const float* pf = qsrc + row * D + l * 8;
    const float4 x = *(const float4*)pf;
    const float4 y = *(const float4*)(pf + 4);
    bf16x8 u;
    u[0] = (short)f2bf(x.x); u[1] = (short)f2bf(x.y);
    u[2] = (short)f2bf(x.z); u[3] = (short)f2bf(x.w);
    u[4] = (short)f2bf(y.x); u[5] = (short)f2bf(y.y);
    u[6] = (short)f2bf(y.z); u[7] = (short)f2bf(y.w);
    *(bf16x8*)&Aq[row * 512 + ((l ^ (row & 7)) << 3)] = u;
  }
  __syncthreads();  // the ONLY barrier

  f32x4 acc[3];
#pragma unroll
  for (int m = 0; m < 3; ++m) acc[m] = (f32x4){0.f, 0.f, 0.f, 0.f};

#pragma unroll
  for (int kk = 0; kk < 16; ++kk) {
    const int k16 = (kk + kb0) & 15;  // staggered K order
    const int aslot = (k16 * 4 + l4) ^ (l15 & 7);
    const bf16x8 af = *(const bf16x8*)&Aq[l15 * 512 + (aslot << 3)];
    const bf16x8 bfq =
        *(const bf16x8*)(Bfrag + ((size_t)(w * 16 + k16) * 64 + l) * 8);
    const bf16x8 bfk =
        *(const bf16x8*)(Bfrag + ((size_t)((4 + w) * 16 + k16) * 64 + l) * 8);
    const bf16x8 bfv =
        *(const bf16x8*)(Bfrag + ((size_t)((8 + w) * 16 + k16) * 64 + l) * 8);
    acc[0] = __builtin_amdgcn_mfma_f32_16x16x32_bf16(bfq, af, acc[0], 0, 0, 0);
    acc[1] = __builtin_amdgcn_mfma_f32_16x16x32_bf16(bfk, af, acc[1], 0, 0, 0);
    acc[2] = __builtin_amdgcn_mfma_f32_16x16x32_bf16(af, bfv, acc[2], 0, 0, 0);
  }

  // ---- Epilogue: bias + packed coalesced fragment stores.
  const int bidx = s0 >> 11;
  const size_t bbase = (size_t)bidx * (S * P);
  const int S0 = s0 & 2047;

  // q/k (swapped): lane holds p = w*16 + l4*4 + r, s = s0 + l15.
  const int p0 = w * 16 + l4 * 4;
  const float4 bq4 = *(const float4*)(bq + p0);
  const float4 bk4 = *(const float4*)(bk + p0);
  const size_t qkoff =
      bbase +
      ((((size_t)(S0 >> 4) * 2 + (p0 >> 5)) * 4 + ((p0 >> 3) & 3)) * 16 +
       l15) * 8 +
      (p0 & 7);
  s16x4 pq, pkk;
  pq[0] = (short)f2bf((acc[0][0] + bq4.x) * SCALE);
  pq[1] = (short)f2bf((acc[0][1] + bq4.y) * SCALE);
  pq[2] = (short)f2bf((acc[0][2] + bq4.z) * SCALE);
  pq[3] = (short)f2bf((acc[0][3] + bq4.w) * SCALE);
  pkk[0] = (short)f2bf(acc[1][0] + bk4.x);
  pkk[1] = (short)f2bf(acc[1][1] + bk4.y);
  pkk[2] = (short)f2bf(acc[1][2] + bk4.z);
  pkk[3] = (short)f2bf(acc[1][3] + bk4.w);
  *(s16x4*)(qfrag + qkoff) = pq;
  *(s16x4*)(kfrag + qkoff) = pkk;

  // v (normal): lane holds p = w*16 + l15, t = S0 + l4*4 + r.
  const float bbv = bv[w * 16 + l15];
  const int chv = ((S0 >> 3) + (l4 >> 1)) & 3;
  const size_t voff =
      bbase + ((((size_t)(S0 >> 5) * 4 + w) * 4 + chv) * 16 + l15) * 8 +
      (l4 & 1) * 4;
  s16x4 pv;
  pv[0] = (short)f2bf(acc[2][0] + bbv);
  pv[1] = (short)f2bf(acc[2][1] + bbv);
  pv[2] = (short)f2bf(acc[2][2] + bbv);
  pv[3] = (short)f2bf(acc[2][3] + bbv);
  *(s16x4*)(vfrag + voff) = pv;
}

// ---------------------------------------------------------------------------
// Kernel 2: flash attention + fused output projection (round-5 version,
// + s_setprio around MFMA clusters).
// Grid 256 x 1024 thr (16 waves, 4 waves/SIMD, 1 block/CU -- LDS-pinned).
// Block = 64 q-rows of one batch (blk&7=batch -> XCD L2 pinning).
// Wave (qg=w&1: 32 rows, th=w>>1: 256-t eighth), 4 windows of 64 t,
// window order staggered by q-tile.  Per-wave e-tile double-buffered.
// QK^T operand-SWAPPED: scores D[t][q] (lane: t-run of 4, q=l15) -> exp
// packs into one s16x4 store per n-tile into the verified layout:
//   elem(q, t) at byte  st*2048 + q*128 + ((t*2) ^ ((q&7)<<4))
// PV reads it back with the verified swizzled ds_read_b128:
//   ae at byte          st*2048 + l15*128 + ((hf*64 + l4*16) ^ ((l15&7)<<4))
// Register plan (observed 64-reg arch budget): #pragma unroll 1 half-window
// loop caps arch peak at ~54 -> zero spill (r5-proven: 124.1us total).
// No barriers in the main loop -> waves sit at different phases -> setprio
// around MFMA clusters lets the CU scheduler favor MFMA-issuing waves (T5).
// Epilogue: all 16 waves dump partials (chunk-XOR-swizzled), all 16 waves
// combine 4 rows each via float4 reads, packed wnorm write, then Wo proj.
// ---------------------------------------------------------------------------
__global__ __launch_bounds__(1024)
__attribute__((amdgpu_waves_per_eu(4, 4))) void attn_fused(
    const unsigned short* __restrict__ qfrag,
    const unsigned short* __restrict__ kfrag,
    const unsigned short* __restrict__ vfrag,
    const unsigned short* __restrict__ Wofrag, const float* __restrict__ bo,
    float* __restrict__ out) {
  // Main loop: e = 16 waves x 8 KB (double-buffered) = 128 KB.
  // Epilogue aliases: pacc [8 th][2 qg][32][64] f32 = 128 KB at offset 0;
  //                   then wnorm [64][64] bf16 = 8 KB at offset 0.
  __shared__ __align__(16) unsigned char smem[131072];
  __shared__ float l_s[16][32];

  const int tid = threadIdx.x;
  const int w = tid >> 6;
  const int lane = tid & 63;
  const int l15 = lane & 15;
  const int l4 = lane >> 4;
  const int qg = w & 1;   // 32-row group
  const int th = w >> 1;  // 256-t eighth

  const int blk = blockIdx.x;
  const int b = blk & 7;
  const int qt = blk >> 3;     // 0..31
  const int s0 = qt * 64;
  const int wst = qt & 3;      // window-phase stagger

  const size_t bbase = (size_t)b * (S * P);
  const unsigned short* qf = qfrag + bbase;
  const unsigned short* kf = kfrag + bbase;
  const unsigned short* vf = vfrag + bbase;

  unsigned char* e_w = smem + w * 8192;  // 8 KB/wave (2 buf x 4 KB)
  const int xm = (l15 & 7) << 4;         // q-row XOR swizzle mask (bytes)

  // q A-fragments: tiles (s0>>4) + qg*2 + st.
  bf16x8 aq[2][2];
#pragma unroll
  for (int st = 0; st < 2; ++st)
#pragma unroll
    for (int h = 0; h < 2; ++h)
      aq[st][h] =
          *(const bf16x8*)(qf +
                           ((size_t)(((s0 >> 4) + qg * 2 + st) * 2 + h) * 64 +
                            lane) *
                               8);

  f32x4 acc[2][4];
#pragma unroll
  for (int st = 0; st < 2; ++st)
#pragma unroll
    for (int pc = 0; pc < 4; ++pc) acc[st][pc] = (f32x4){0.f, 0.f, 0.f, 0.f};
  float lpart[2] = {0.f, 0.f};

  for (int win = 0; win < 4; ++win) {
    const int wi = (win + wst) & 3;           // staggered window
    const int t0 = th * 256 + wi * 64;
    unsigned char* epb = e_w + (win & 1) * 4096;  // double buffer

    // Two 32-t half-windows; runtime loop caps register liveness.
#pragma unroll 1
    for (int hf = 0; hf < 2; ++hf) {
      // k fragments for this half (4 coalesced 1 KB loads).
      bf16x8 bkh[2][2];
#pragma unroll
      for (int j = 0; j < 2; ++j)
#pragma unroll
        for (int h = 0; h < 2; ++h)
          bkh[j][h] =
              *(const bf16x8*)(kf + ((size_t)(((t0 >> 4) + hf * 2 + j) * 2 +
                                              h) * 64 + lane) * 8);

      // QK^T + exp/pack/store per subtile.  t = (hf*2+j)*16 + l4*4 + r.
#pragma unroll
      for (int st = 0; st < 2; ++st) {
        f32x4 sc[2];
        __builtin_amdgcn_s_setprio(1);
#pragma unroll
        for (int j = 0; j < 2; ++j) {
          f32x4 c = (f32x4){0.f, 0.f, 0.f, 0.f};
          c = __builtin_amdgcn_mfma_f32_16x16x32_bf16(bkh[j][0], aq[st][0], c,
                                                      0, 0, 0);
          sc[j] = __builtin_amdgcn_mfma_f32_16x16x32_bf16(bkh[j][1], aq[st][1],
                                                          c, 0, 0, 0);
        }
        __builtin_amdgcn_s_setprio(0);
#pragma unroll
        for (int j = 0; j < 2; ++j) {
          s16x4 pk;
#pragma unroll
          for (int r = 0; r < 4; ++r) pk[r] = (short)f2bf(__expf(sc[j][r]));
#pragma unroll
          for (int r = 0; r < 4; ++r)
            lpart[st] += bf2f((unsigned short)pk[r]);
          *(s16x4*)(epb + st * 2048 + l15 * 128 +
                    (((hf * 2 + j) * 32 + l4 * 8) ^ xm)) = pk;
        }
      }

      // v fragments for this half (4 coalesced 1 KB loads).
      bf16x8 bvh[4];
#pragma unroll
      for (int pc = 0; pc < 4; ++pc)
        bvh[pc] =
            *(const bf16x8*)(vf + ((size_t)(((t0 >> 5) + hf) * 4 + pc) * 64 +
                                   lane) * 8);

      // PV for this half (same-wave DS ordering makes stores visible).
#pragma unroll
      for (int st = 0; st < 2; ++st) {
        const bf16x8 ae = *(const bf16x8*)(epb + st * 2048 + l15 * 128 +
                                           ((hf * 64 + l4 * 16) ^ xm));
        __builtin_amdgcn_s_setprio(1);
#pragma unroll
        for (int pc = 0; pc < 4; ++pc)
          acc[st][pc] = __builtin_amdgcn_mfma_f32_16x16x32_bf16(
              ae, bvh[pc], acc[st][pc], 0, 0, 0);
        __builtin_amdgcn_s_setprio(0);
      }
    }
  }

  // ---- Row-sums: intra-lane over t, then across the 4 l4-groups.
#pragma unroll
  for (int st = 0; st < 2; ++st) {
    float v = lpart[st];
    v += __shfl_xor(v, 16, 64);
    v += __shfl_xor(v, 32, 64);
    if (l4 == 0) l_s[w][st * 16 + l15] = v;
  }

  __syncthreads();  // all waves done with e-tiles before pacc aliases them

  // ---- Dump ALL 16 waves' partials.  pacc [8 th][2 qg][32][64] f32 (128KB),
  // wave index (th*2+qg) == w.  Chunk-XOR swizzle (pc ^ l4) keeps the
  // scalar stores spread across 16B slots.
  float* pacc = (float*)smem;
#pragma unroll
  for (int st = 0; st < 2; ++st)
#pragma unroll
    for (int pc = 0; pc < 4; ++pc)
#pragma unroll
      for (int r = 0; r < 4; ++r) {
        const int row = st * 16 + l4 * 4 + r;
        pacc[((size_t)w * 32 + row) * 64 + ((pc ^ l4) * 16) + l15] =
            acc[st][pc][r];
      }
  __syncthreads();

  // ---- Distributed combine: wave w sums rows w*4..w*4+3, lane = 4 cols.
  const int R = w * 4 + l4;        // global row 0..63
  const int qgR = R >> 5;
  const int r32 = R & 31;
  const int csw = (r32 >> 2) & 3;  // matches writer swizzle (= writer's l4)
  const int coff = (((l15 >> 2) ^ csw) * 16) + (l15 & 3) * 4;
  float4 s4 = {0.f, 0.f, 0.f, 0.f};
#pragma unroll
  for (int t8 = 0; t8 < 8; ++t8) {
    const float4 p4 =
        *(const float4*)&pacc[((size_t)(t8 * 2 + qgR) * 32 + r32) * 64 + coff];
    s4.x += p4.x; s4.y += p4.y; s4.z += p4.z; s4.w += p4.w;
  }
  float ls = 0.f;
#pragma unroll
  for (int t8 = 0; t8 < 8; ++t8) ls += l_s[t8 * 2 + qgR][r32];
  const float inv = 1.f / ls;
  s16x4 wn;
  wn[0] = (short)f2bf(s4.x * inv);
  wn[1] = (short)f2bf(s4.y * inv);
  wn[2] = (short)f2bf(s4.z * inv);
  wn[3] = (short)f2bf(s4.w * inv);
  __syncthreads();  // all pacc reads done before wnorm overwrites it

  unsigned short* wnorm = (unsigned short*)smem;  // [64][64] bf16 at offset 0
  *(s16x4*)&wnorm[R * 64 + l15 * 4] = wn;
  __syncthreads();

  // ---- Fused output projection: 16 waves = (4 row-subtiles) x (4 col-128s).
  const int sub = w & 3;    // 16-row subtile
  const int chq = w >> 2;   // 128-col quarter
  const bf16x8 a0 = *(const bf16x8*)&wnorm[(sub * 16 + l15) * 64 + l4 * 8];
  const bf16x8 a1 =
      *(const bf16x8*)&wnorm[(sub * 16 + l15) * 64 + 32 + l4 * 8];
  const size_t orow0 = (size_t)b * S + s0 + sub * 16;
#pragma unroll
  for (int ct = 0; ct < 8; ++ct) {
    const int ctg = chq * 8 + ((ct + (blk & 7)) & 7);  // staggered Wo tiles
    const bf16x8 b0 =
        *(const bf16x8*)(Wofrag + ((size_t)(ctg * 2 + 0) * 64 + lane) * 8);
    const bf16x8 b1 =
        *(const bf16x8*)(Wofrag + ((size_t)(ctg * 2 + 1) * 64 + lane) * 8);
    f32x4 c = (f32x4){0.f, 0.f, 0.f, 0.f};
    c = __builtin_amdgcn_mfma_f32_16x16x32_bf16(a0, b0, c, 0, 0, 0);
    c = __builtin_amdgcn_mfma_f32_16x16x32_bf16(a1, b1, c, 0, 0, 0);
    const int col = ctg * 16 + l15;
    const float bb = bo[col];
#pragma unroll
    for (int r = 0; r < 4; ++r)
      out[(orow0 + l4 * 4 + r) * D + col] = c[r] + bb;
  }
}

// ---------------------------------------------------------------------------
extern "C" void kernel_launch(void* const* d_in, const int* in_sizes, int n_in,
                              void* d_out, int out_size, void* d_ws,
                              size_t ws_size, hipStream_t stream) {
  const float* query = (const float*)d_in[0];
  // d_in[1] = attention_mask: unused (per-row additive constant -> softmax no-op)
  const float* Wq = (const float*)d_in[2];
  const float* bq = (const float*)d_in[3];
  const float* Wk = (const float*)d_in[4];
  const float* bk = (const float*)d_in[5];
  const float* Wv = (const float*)d_in[6];
  const float* bv = (const float*)d_in[7];
  const float* Wo = (const float*)d_in[8];
  const float* bo = (const float*)d_in[9];
  float* out = (float*)d_out;

  // Workspace (bf16): qfrag 2MB | kfrag 2MB | vfrag 2MB | Bfrag 192KB | Wofrag 64KB
  const size_t proj = (size_t)B * S * P;  // 1,048,576
  unsigned short* qfr = (unsigned short*)d_ws;
  unsigned short* kfr = qfr + proj;
  unsigned short* vfr = kfr + proj;
  unsigned short* Bfrag = vfr + proj;
  unsigned short* Wofrag = Bfrag + 192 * 512;

  prep_w<<<384, 256, 0, stream>>>(Wq, Wk, Wv, Wo, Bfrag, Wofrag);
  qkv_mfma<<<1024, 256, 0, stream>>>(query, Bfrag, bq, bk, bv, qfr, kfr, vfr);
  attn_fused<<<256, 1024, 0, stream>>>(qfr, kfr, vfr, Wofrag, bo, out);
}